// Round 13
// baseline (310.605 us; speedup 1.0000x reference)
//
#include <hip/hip_runtime.h>
#include <hip/hip_bf16.h>

typedef __attribute__((ext_vector_type(8))) short s8v;   // 8 x bf16
typedef __attribute__((ext_vector_type(4))) float f32x4; // MFMA acc

__device__ __forceinline__ float sigf(float x) { return 1.0f / (1.0f + __expf(-x)); }
__device__ __forceinline__ float tanh_fast(float x) { return 1.0f - 2.0f / (1.0f + __expf(2.0f * x)); }
__device__ __forceinline__ ushort f2bf(float f) {
    union { __hip_bfloat16 b; ushort u; } v; v.b = __float2bfloat16(f); return v.u;
}
__device__ __forceinline__ float bf2f(ushort u) {
    union { float f; unsigned int i; } v; v.i = ((unsigned int)u) << 16; return v.f;
}

// ---------------- prepass: pack weights + fused bias + bf16 embedding gather ----------------
// Bpack: (((bn*12 + kk)*4 + seg)*128 + nl)*8 + t, col order nl -> g=(nl>>4)&3,
// j = bn*32 + (nl>>6)*16 + (nl&15)  => after MFMA each lane holds all 4 gates of one j.
__global__ __launch_bounds__(256) void prepass(
    const int* __restrict__ nt, const float* __restrict__ na,
    const float* __restrict__ emb,
    const float* __restrict__ Wih, const float* __restrict__ Whh,
    const float* __restrict__ bih, const float* __restrict__ bhh,
    ushort* __restrict__ Bpack, float* __restrict__ bsum,
    ushort* __restrict__ xall)
{
    const int gid = blockIdx.x * 256 + threadIdx.x;
    if (gid < 24576) {
        const int nl  = gid & 127;
        const int seg = (gid >> 7) & 3;
        const int rest = gid >> 9;
        const int kk = rest % 12;
        const int bn = rest / 12;
        const int g  = (nl >> 4) & 3;
        const int j  = bn * 32 + ((nl >> 6) << 4) + (nl & 15);
        const int row = g * 256 + j;
        const int k = kk * 32 + seg * 8;
        const float* src = (k < 128) ? (Wih + (size_t)row * 128 + k)
                                     : (Whh + (size_t)row * 256 + (k - 128));
        float4 w0 = *(const float4*)(src);
        float4 w1 = *(const float4*)(src + 4);
        ushort o[8] = { f2bf(w0.x), f2bf(w0.y), f2bf(w0.z), f2bf(w0.w),
                        f2bf(w1.x), f2bf(w1.y), f2bf(w1.z), f2bf(w1.w) };
        *(s8v*)(Bpack + (size_t)gid * 8) = *(const s8v*)o;
    }
    if (gid < 512) {
        const int row = (gid >> 7) * 256 + (gid & 127);
        bsum[gid] = bih[row] + bhh[row];
    }
    const int node = gid >> 4;
    const int run  = gid & 15;
    if (node < 65535) {
        const int ty = nt[node];
        const float* src = emb + (size_t)ty * 128 + run * 8;
        float4 w0 = *(const float4*)src;
        float4 w1 = *(const float4*)(src + 4);
        if (run == 15 && (ty == 1 || ty == 2)) w1.w = na[node];
        ushort o[8] = { f2bf(w0.x), f2bf(w0.y), f2bf(w0.z), f2bf(w0.w),
                        f2bf(w1.x), f2bf(w1.y), f2bf(w1.z), f2bf(w1.w) };
        *(s8v*)(xall + (size_t)node * 128 + run * 8) = *(const s8v*)o;
    }
}

#define MFMA_(a, b, c) __builtin_amdgcn_mfma_f32_16x16x32_bf16(a, b, c, 0, 0, 0)

// 16 MFMAs: 4 row-groups (a0..a3) x 4 gate-fragments (bt0..bt3)
#define STEP16 do { \
    acc00 = MFMA_(a0, bt0, acc00); acc10 = MFMA_(a1, bt0, acc10); \
    acc20 = MFMA_(a2, bt0, acc20); acc30 = MFMA_(a3, bt0, acc30); \
    acc01 = MFMA_(a0, bt1, acc01); acc11 = MFMA_(a1, bt1, acc11); \
    acc21 = MFMA_(a2, bt1, acc21); acc31 = MFMA_(a3, bt1, acc31); \
    acc02 = MFMA_(a0, bt2, acc02); acc12 = MFMA_(a1, bt2, acc12); \
    acc22 = MFMA_(a2, bt2, acc22); acc32 = MFMA_(a3, bt2, acc32); \
    acc03 = MFMA_(a0, bt3, acc03); acc13 = MFMA_(a1, bt3, acc13); \
    acc23 = MFMA_(a2, bt3, acc23); acc33 = MFMA_(a3, bt3, acc33); } while (0)

#define LDB_LDS(KK) do { \
    bt0 = *(const s8v*)(BXP + (size_t)(((w * 4 + KK) * 4 + 0) * 64 + lane) * 8); \
    bt1 = *(const s8v*)(BXP + (size_t)(((w * 4 + KK) * 4 + 1) * 64 + lane) * 8); \
    bt2 = *(const s8v*)(BXP + (size_t)(((w * 4 + KK) * 4 + 2) * 64 + lane) * 8); \
    bt3 = *(const s8v*)(BXP + (size_t)(((w * 4 + KK) * 4 + 3) * 64 + lane) * 8); } while (0)

#define LDB_G(KK) do { \
    bt0 = *(const s8v*)(pb + (size_t)KK * 4096 +   0); \
    bt1 = *(const s8v*)(pb + (size_t)KK * 4096 + 128); \
    bt2 = *(const s8v*)(pb + (size_t)KK * 4096 + 256); \
    bt3 = *(const s8v*)(pb + (size_t)KK * 4096 + 384); } while (0)

#define LDA4(P0, P1, P2, P3, OFF) do { \
    a0 = *(const s8v*)(P0 + OFF); a1 = *(const s8v*)(P1 + OFF); \
    a2 = *(const s8v*)(P2 + OFF); a3 = *(const s8v*)(P3 + OFF); } while (0)

#define EPI(MI, R) do { \
    const int m = m0 + MI * 16 + seg * 4 + R; \
    if (m < npb) { \
        const int g = start + rb + m; \
        const float gi = acc##MI##0[R] + bi; \
        const float gf = acc##MI##1[R] + bf_; \
        const float gg = acc##MI##2[R] + bg; \
        const float go = acc##MI##3[R] + bo; \
        const float c0v = leaf_lvl ? 0.0f : c_all[(size_t)g * 128 + j]; \
        const float cn = sigf(gf) * c0v + sigf(gi) * tanh_fast(gg); \
        const float hn = sigf(go) * tanh_fast(cn); \
        h_all[(size_t)g * 128 + j] = f2bf(hn); \
        if (g & 1) c_all[(size_t)((g - 1) >> 1) * 128 + j] = cn; \
    } } while (0)

// ---------------- multi-level kernel: 64-row x 512-col tiles, x-part B in LDS ----------------
// 8 waves, wave w owns cols (bn=w>>1, wn=w&1): 16 j x 4 gates. All waves cover the same rows.
// Block b owns subtree rows [b*npb, (b+1)*npb) per level; children always in-block (heap h_all/c_all).
// B kk 0..3 (the x*Wih part, 128KB) staged once in LDS; kk 4..11 streamed from L2 per tile.
template<bool LEAF, bool HEAD>
__global__ __launch_bounds__(512, 2) void levels_kernel(
    const ushort* __restrict__ xall,
    const ushort* __restrict__ Bpack, const float* __restrict__ bsum,
    ushort* __restrict__ h_all, float* __restrict__ c_all,
    int lvl_top, int nlv,
    const float* __restrict__ W1, const float* __restrict__ b1,
    const float* __restrict__ W2, const float* __restrict__ b2,
    const float* __restrict__ vmask, float* __restrict__ out)
{
    __shared__ __align__(16) ushort BXP[65536];  // 128 KB: kk 0..3, [w][kk][f][lane][8]
    __shared__ float hs[128];
    __shared__ float as[128];

    const int tid  = threadIdx.x;
    const int lane = tid & 63;
    const int w    = tid >> 6;
    const int bn = w >> 1, wn = w & 1;
    const int lc = lane & 15, seg = lane >> 4;
    const int koff = seg * 8;

    const ushort* pb = Bpack + (size_t)bn * 49152 + (size_t)seg * 1024
                             + (size_t)(wn * 64 + lc) * 8;

    // stage x-part B (kk 0..3) into LDS once
    #pragma unroll
    for (int kk = 0; kk < 4; ++kk)
        #pragma unroll
        for (int f = 0; f < 4; ++f) {
            s8v t = *(const s8v*)(pb + (size_t)kk * 4096 + f * 128);
            *(s8v*)(BXP + (size_t)(((w * 4 + kk) * 4 + f) * 64 + lane) * 8) = t;
        }
    __syncthreads();

    const int j = bn * 32 + wn * 16 + lc;
    const float bi  = bsum[j];
    const float bf_ = bsum[128 + j];
    const float bg  = bsum[256 + j];
    const float bo  = bsum[384 + j];

    for (int li = 0; li < nlv; ++li) {
        const int L = lvl_top - li;
        const int n_l = 1 << L;
        const int start = n_l - 1;
        int npb = n_l / (int)gridDim.x;
        if (npb < 1) npb = 1;
        const int rb = blockIdx.x * npb;
        const bool leaf_lvl = LEAF && (li == 0);

        for (int m0 = 0; m0 < npb; m0 += 64) {
            int g0, g1, g2, g3;
            { int mA = m0 + lc;      if (mA > npb - 1) mA = npb - 1; g0 = start + rb + mA; }
            { int mA = m0 + 16 + lc; if (mA > npb - 1) mA = npb - 1; g1 = start + rb + mA; }
            { int mA = m0 + 32 + lc; if (mA > npb - 1) mA = npb - 1; g2 = start + rb + mA; }
            { int mA = m0 + 48 + lc; if (mA > npb - 1) mA = npb - 1; g3 = start + rb + mA; }
            const ushort* px0 = xall + (size_t)g0 * 128 + koff;
            const ushort* px1 = xall + (size_t)g1 * 128 + koff;
            const ushort* px2 = xall + (size_t)g2 * 128 + koff;
            const ushort* px3 = xall + (size_t)g3 * 128 + koff;

            f32x4 acc00={0.f,0.f,0.f,0.f}, acc01={0.f,0.f,0.f,0.f}, acc02={0.f,0.f,0.f,0.f}, acc03={0.f,0.f,0.f,0.f};
            f32x4 acc10={0.f,0.f,0.f,0.f}, acc11={0.f,0.f,0.f,0.f}, acc12={0.f,0.f,0.f,0.f}, acc13={0.f,0.f,0.f,0.f};
            f32x4 acc20={0.f,0.f,0.f,0.f}, acc21={0.f,0.f,0.f,0.f}, acc22={0.f,0.f,0.f,0.f}, acc23={0.f,0.f,0.f,0.f};
            f32x4 acc30={0.f,0.f,0.f,0.f}, acc31={0.f,0.f,0.f,0.f}, acc32={0.f,0.f,0.f,0.f}, acc33={0.f,0.f,0.f,0.f};

            s8v a0, a1, a2, a3, bt0, bt1, bt2, bt3;
            // kk 0..3: x-part, B from LDS
            LDA4(px0, px1, px2, px3,  0); LDB_LDS(0); STEP16;
            LDA4(px0, px1, px2, px3, 32); LDB_LDS(1); STEP16;
            LDA4(px0, px1, px2, px3, 64); LDB_LDS(2); STEP16;
            LDA4(px0, px1, px2, px3, 96); LDB_LDS(3); STEP16;

            if (!leaf_lvl) {
                const ushort* pl0 = h_all + (size_t)(2 * g0 + 1) * 128 + koff;
                const ushort* pl1 = h_all + (size_t)(2 * g1 + 1) * 128 + koff;
                const ushort* pl2 = h_all + (size_t)(2 * g2 + 1) * 128 + koff;
                const ushort* pl3 = h_all + (size_t)(2 * g3 + 1) * 128 + koff;
                // kk 4..7: left-child h, B streamed
                LDA4(pl0, pl1, pl2, pl3,  0); LDB_G(4); STEP16;
                LDA4(pl0, pl1, pl2, pl3, 32); LDB_G(5); STEP16;
                LDA4(pl0, pl1, pl2, pl3, 64); LDB_G(6); STEP16;
                LDA4(pl0, pl1, pl2, pl3, 96); LDB_G(7); STEP16;
                const ushort* pr0 = h_all + (size_t)(2 * g0 + 2) * 128 + koff;
                const ushort* pr1 = h_all + (size_t)(2 * g1 + 2) * 128 + koff;
                const ushort* pr2 = h_all + (size_t)(2 * g2 + 2) * 128 + koff;
                const ushort* pr3 = h_all + (size_t)(2 * g3 + 2) * 128 + koff;
                // kk 8..11: right-child h, B streamed
                LDA4(pr0, pr1, pr2, pr3,  0); LDB_G(8);  STEP16;
                LDA4(pr0, pr1, pr2, pr3, 32); LDB_G(9);  STEP16;
                LDA4(pr0, pr1, pr2, pr3, 64); LDB_G(10); STEP16;
                LDA4(pr0, pr1, pr2, pr3, 96); LDB_G(11); STEP16;
            }

            EPI(0,0); EPI(0,1); EPI(0,2); EPI(0,3);
            EPI(1,0); EPI(1,1); EPI(1,2); EPI(1,3);
            EPI(2,0); EPI(2,1); EPI(2,2); EPI(2,3);
            EPI(3,0); EPI(3,1); EPI(3,2); EPI(3,3);
        }
        __syncthreads();
    }

    if (HEAD && blockIdx.x == 0) {
        if (tid < 128) hs[tid] = bf2f(h_all[tid]);
        __syncthreads();
        if (tid < 128) {
            float a1h = b1[tid];
            #pragma unroll 4
            for (int k = 0; k < 128; ++k) a1h = fmaf(hs[k], W1[tid * 128 + k], a1h);
            as[tid] = fmaxf(a1h, 0.0f);
        }
        __syncthreads();
        if (tid < 32) {
            float l = b2[tid];
            #pragma unroll 4
            for (int k = 0; k < 128; ++k) l = fmaf(as[k], W2[tid * 128 + k], l);
            l = (l + logf(vmask[tid])) * (1.0f / 3.0f);
            float mx = l;
            #pragma unroll
            for (int o = 16; o >= 1; o >>= 1) mx = fmaxf(mx, __shfl_xor(mx, o, 32));
            const float e = __expf(l - mx);
            float s = e;
            #pragma unroll
            for (int o = 16; o >= 1; o >>= 1) s += __shfl_xor(s, o, 32);
            out[tid] = e / s;
        }
    }
}

extern "C" void kernel_launch(void* const* d_in, const int* in_sizes, int n_in,
                              void* d_out, int out_size, void* d_ws, size_t ws_size,
                              hipStream_t stream)
{
    const int*   node_types = (const int*)  d_in[0];
    const float* node_args  = (const float*)d_in[1];
    const float* vmask      = (const float*)d_in[2];
    const float* emb        = (const float*)d_in[3];
    const float* Wih        = (const float*)d_in[4];
    const float* Whh        = (const float*)d_in[5];
    const float* bih        = (const float*)d_in[6];
    const float* bhh        = (const float*)d_in[7];
    const float* W1         = (const float*)d_in[8];
    const float* b1         = (const float*)d_in[9];
    const float* W2         = (const float*)d_in[10];
    const float* b2         = (const float*)d_in[11];

    char* w = (char*)d_ws;
    ushort* xall  = (ushort*)(w);                 // 65536*128*2 = 16,777,216
    ushort* Bpack = (ushort*)(w + 16777216);      // 393,216
    float*  bsum  = (float*) (w + 17170432);      // 2,048
    ushort* h_all = (ushort*)(w + 17172480);      // 65536*128*2 = 16,777,216
    float*  c_all = (float*) (w + 33949696);      // 32768*128*4 = 16,777,216

    float* out = (float*)d_out;

    prepass<<<4096, 256, 0, stream>>>(node_types, node_args, emb,
                                      Wih, Whh, bih, bhh, Bpack, bsum, xall);

    levels_kernel<true,  false><<<256, 512, 0, stream>>>(
        xall, Bpack, bsum, h_all, c_all, 15, 4, W1, b1, W2, b2, vmask, out);
    levels_kernel<false, false><<<32,  512, 0, stream>>>(
        xall, Bpack, bsum, h_all, c_all, 11, 4, W1, b1, W2, b2, vmask, out);
    levels_kernel<false, true ><<<1,   512, 0, stream>>>(
        xall, Bpack, bsum, h_all, c_all, 7, 8, W1, b1, W2, b2, vmask, out);
}

// Round 14
// 204.420 us; speedup vs baseline: 1.5194x; 1.5194x over previous
//
#include <hip/hip_runtime.h>
#include <hip/hip_bf16.h>

typedef __attribute__((ext_vector_type(8))) short s8v;   // 8 x bf16
typedef __attribute__((ext_vector_type(4))) float f32x4; // MFMA acc

__device__ __forceinline__ float sigf(float x) { return 1.0f / (1.0f + __expf(-x)); }
__device__ __forceinline__ float tanh_fast(float x) { return 1.0f - 2.0f / (1.0f + __expf(2.0f * x)); }
__device__ __forceinline__ ushort f2bf(float f) {
    union { __hip_bfloat16 b; ushort u; } v; v.b = __float2bfloat16(f); return v.u;
}

// ---------------- prepass: pack weights + fused bias + bf16 embedding gather ----------------
// Bpack: (((bn*12 + kk)*4 + seg)*128 + nl)*8 + t, col order nl -> g=(nl>>4)&3,
// j = bn*32 + (nl>>6)*16 + (nl&15)  => after MFMA each lane holds all 4 gates of one j.
__global__ __launch_bounds__(256) void prepass(
    const int* __restrict__ nt, const float* __restrict__ na,
    const float* __restrict__ emb,
    const float* __restrict__ Wih, const float* __restrict__ Whh,
    const float* __restrict__ bih, const float* __restrict__ bhh,
    ushort* __restrict__ Bpack, float* __restrict__ bsum,
    ushort* __restrict__ xall)
{
    const int gid = blockIdx.x * 256 + threadIdx.x;
    if (gid < 24576) {
        const int nl  = gid & 127;
        const int seg = (gid >> 7) & 3;
        const int rest = gid >> 9;
        const int kk = rest % 12;
        const int bn = rest / 12;
        const int g  = (nl >> 4) & 3;
        const int j  = bn * 32 + ((nl >> 6) << 4) + (nl & 15);
        const int row = g * 256 + j;
        const int k = kk * 32 + seg * 8;
        const float* src = (k < 128) ? (Wih + (size_t)row * 128 + k)
                                     : (Whh + (size_t)row * 256 + (k - 128));
        float4 w0 = *(const float4*)(src);
        float4 w1 = *(const float4*)(src + 4);
        ushort o[8] = { f2bf(w0.x), f2bf(w0.y), f2bf(w0.z), f2bf(w0.w),
                        f2bf(w1.x), f2bf(w1.y), f2bf(w1.z), f2bf(w1.w) };
        *(s8v*)(Bpack + (size_t)gid * 8) = *(const s8v*)o;
    }
    if (gid < 512) {
        const int row = (gid >> 7) * 256 + (gid & 127);
        bsum[gid] = bih[row] + bhh[row];
    }
    const int node = gid >> 4;
    const int run  = gid & 15;
    if (node < 65535) {
        const int ty = nt[node];
        const float* src = emb + (size_t)ty * 128 + run * 8;
        float4 w0 = *(const float4*)src;
        float4 w1 = *(const float4*)(src + 4);
        if (run == 15 && (ty == 1 || ty == 2)) w1.w = na[node];
        ushort o[8] = { f2bf(w0.x), f2bf(w0.y), f2bf(w0.z), f2bf(w0.w),
                        f2bf(w1.x), f2bf(w1.y), f2bf(w1.z), f2bf(w1.w) };
        *(s8v*)(xall + (size_t)node * 128 + run * 8) = *(const s8v*)o;
    }
}

// ---------------- single-level GEMM + register LSTM epilogue (R6-proven) ----------------
// Block: 64 rows x 128 cols (one bn of 512 eff). 4 waves = 2(wm) x 2(wn). VGPR ~72.
__global__ __launch_bounds__(256) void level_gemm(
    const ushort* __restrict__ xall,
    const ushort* __restrict__ Bpack, const float* __restrict__ bsum,
    const ushort* __restrict__ h_in, const float* __restrict__ c_in,
    ushort* __restrict__ h_out, float* __restrict__ c_out,
    int start, int n_l, int has_h)
{
    const int tid  = threadIdx.x;
    const int lane = tid & 63;
    const int wave = tid >> 6;
    const int wm = wave >> 1, wn = wave & 1;
    const int lc = lane & 15, seg = lane >> 4;
    const int koff = seg * 8;
    const int bn = blockIdx.y;
    const int m0 = blockIdx.x * 64;

    const ushort* px[2];
    const ushort* ph[2][2];
    #pragma unroll
    for (int mi = 0; mi < 2; ++mi) {
        int m = m0 + wm * 32 + mi * 16 + lc;
        int mc = m < n_l ? m : n_l - 1;
        px[mi]    = xall + (size_t)(start + mc) * 128 + koff;
        ph[mi][0] = h_in + (size_t)(2 * mc) * 128 + koff;
        ph[mi][1] = h_in + (size_t)(2 * mc + 1) * 128 + koff;
    }
    const ushort* pb = Bpack + (size_t)bn * 49152 + (size_t)seg * 1024
                             + (size_t)(wn * 64 + lc) * 8;

    f32x4 acc[2][4];
    #pragma unroll
    for (int mi = 0; mi < 2; ++mi)
        #pragma unroll
        for (int f = 0; f < 4; ++f) acc[mi][f] = (f32x4){0.f, 0.f, 0.f, 0.f};

    #pragma unroll
    for (int kk = 0; kk < 4; ++kk) {
        s8v a0 = *(const s8v*)(px[0] + kk * 32);
        s8v a1 = *(const s8v*)(px[1] + kk * 32);
        #pragma unroll
        for (int f = 0; f < 4; ++f) {
            s8v b = *(const s8v*)(pb + (size_t)kk * 4096 + f * 128);
            acc[0][f] = __builtin_amdgcn_mfma_f32_16x16x32_bf16(a0, b, acc[0][f], 0, 0, 0);
            acc[1][f] = __builtin_amdgcn_mfma_f32_16x16x32_bf16(a1, b, acc[1][f], 0, 0, 0);
        }
    }
    if (has_h) {
        #pragma unroll
        for (int kk = 0; kk < 8; ++kk) {
            const int hi = kk >> 2, off = (kk & 3) * 32;
            s8v a0 = *(const s8v*)(ph[0][hi] + off);
            s8v a1 = *(const s8v*)(ph[1][hi] + off);
            #pragma unroll
            for (int f = 0; f < 4; ++f) {
                s8v b = *(const s8v*)(pb + (size_t)(kk + 4) * 4096 + f * 128);
                acc[0][f] = __builtin_amdgcn_mfma_f32_16x16x32_bf16(a0, b, acc[0][f], 0, 0, 0);
                acc[1][f] = __builtin_amdgcn_mfma_f32_16x16x32_bf16(a1, b, acc[1][f], 0, 0, 0);
            }
        }
    }

    const int j = bn * 32 + wn * 16 + lc;
    const float bi = bsum[j];
    const float bf = bsum[128 + j];
    const float bg = bsum[256 + j];
    const float bo = bsum[384 + j];
    #pragma unroll
    for (int mi = 0; mi < 2; ++mi) {
        const int tb = m0 + wm * 32 + mi * 16 + seg * 4;
        #pragma unroll
        for (int r = 0; r < 4; ++r) {
            const int m = tb + r;
            if (m < n_l) {
                const float gi = acc[mi][0][r] + bi;
                const float gf = acc[mi][1][r] + bf;
                const float gg = acc[mi][2][r] + bg;
                const float go = acc[mi][3][r] + bo;
                const float c0 = has_h ? c_in[(size_t)m * 128 + j] : 0.0f;
                const float cn = sigf(gf) * c0 + sigf(gi) * tanh_fast(gg);
                const float hn = sigf(go) * tanh_fast(cn);
                h_out[(size_t)m * 128 + j] = f2bf(hn);
                if (!(m & 1)) c_out[(size_t)(m >> 1) * 128 + j] = cn;
            }
        }
    }
}

// ---------------- two-level pair kernel (R7-proven) ----------------
__global__ __launch_bounds__(512) void pair_gemm(
    const ushort* __restrict__ xall,
    const ushort* __restrict__ Bpack, const float* __restrict__ bsum,
    const ushort* __restrict__ h_in, const float* __restrict__ c_in,
    ushort* __restrict__ h_out, float* __restrict__ c_out,
    int startC, int startP, int nP, int has_h)
{
    __shared__ __align__(16) ushort hC[64][136];
    __shared__ float cC[32][132];

    const int tid  = threadIdx.x;
    const int lane = tid & 63;
    const int wave = tid >> 6;
    const int lc = lane & 15, seg = lane >> 4;
    const int koff = seg * 8;
    const int nC = 2 * nP;
    const int b = blockIdx.x;

    // ===== stage 1: children, M=64, N=512 =====
    {
        const int wm2 = wave >> 2;
        const int bn  = wave & 3;
        const ushort* px[2];
        const ushort* ph[2][2];
        #pragma unroll
        for (int mi = 0; mi < 2; ++mi) {
            int mloc = wm2 * 32 + mi * 16 + lc;
            int cg = 64 * b + mloc;
            int cgc = cg < nC ? cg : nC - 1;
            px[mi]    = xall + (size_t)(startC + cgc) * 128 + koff;
            ph[mi][0] = h_in + (size_t)(2 * cgc) * 128 + koff;
            ph[mi][1] = h_in + (size_t)(2 * cgc + 1) * 128 + koff;
        }
        const ushort* pb = Bpack + (size_t)bn * 49152 + (size_t)seg * 1024
                                 + (size_t)lc * 8;

        f32x4 acc[2][8];
        #pragma unroll
        for (int mi = 0; mi < 2; ++mi)
            #pragma unroll
            for (int f = 0; f < 8; ++f) acc[mi][f] = (f32x4){0.f, 0.f, 0.f, 0.f};

        #pragma unroll
        for (int kk = 0; kk < 4; ++kk) {
            s8v a0 = *(const s8v*)(px[0] + kk * 32);
            s8v a1 = *(const s8v*)(px[1] + kk * 32);
            #pragma unroll
            for (int f = 0; f < 8; ++f) {
                s8v bb = *(const s8v*)(pb + (size_t)kk * 4096 + f * 128);
                acc[0][f] = __builtin_amdgcn_mfma_f32_16x16x32_bf16(a0, bb, acc[0][f], 0, 0, 0);
                acc[1][f] = __builtin_amdgcn_mfma_f32_16x16x32_bf16(a1, bb, acc[1][f], 0, 0, 0);
            }
        }
        if (has_h) {
            #pragma unroll
            for (int kk = 0; kk < 8; ++kk) {
                const int hi = kk >> 2, off = (kk & 3) * 32;
                s8v a0 = *(const s8v*)(ph[0][hi] + off);
                s8v a1 = *(const s8v*)(ph[1][hi] + off);
                #pragma unroll
                for (int f = 0; f < 8; ++f) {
                    s8v bb = *(const s8v*)(pb + (size_t)(kk + 4) * 4096 + f * 128);
                    acc[0][f] = __builtin_amdgcn_mfma_f32_16x16x32_bf16(a0, bb, acc[0][f], 0, 0, 0);
                    acc[1][f] = __builtin_amdgcn_mfma_f32_16x16x32_bf16(a1, bb, acc[1][f], 0, 0, 0);
                }
            }
        }
        #pragma unroll
        for (int bh = 0; bh < 2; ++bh) {
            const int j = bn * 32 + bh * 16 + lc;
            const float bi = bsum[j];
            const float bf = bsum[128 + j];
            const float bg = bsum[256 + j];
            const float bo = bsum[384 + j];
            #pragma unroll
            for (int mi = 0; mi < 2; ++mi) {
                #pragma unroll
                for (int r = 0; r < 4; ++r) {
                    const int mloc = wm2 * 32 + mi * 16 + seg * 4 + r;
                    const int cg = 64 * b + mloc;
                    if (cg < nC) {
                        const float gi = acc[mi][bh * 4 + 0][r] + bi;
                        const float gf = acc[mi][bh * 4 + 1][r] + bf;
                        const float gg = acc[mi][bh * 4 + 2][r] + bg;
                        const float go = acc[mi][bh * 4 + 3][r] + bo;
                        const float c0 = has_h ? c_in[(size_t)cg * 128 + j] : 0.0f;
                        const float cn = sigf(gf) * c0 + sigf(gi) * tanh_fast(gg);
                        const float hn = sigf(go) * tanh_fast(cn);
                        hC[mloc][j] = f2bf(hn);
                        if (!(mloc & 1)) cC[mloc >> 1][j] = cn;
                    }
                }
            }
        }
    }
    __syncthreads();

    // ===== stage 2: parents, M=32, N=512 =====
    {
        const int bn = wave >> 1;
        const int wn = wave & 1;
        const ushort* px[2];
        int mcl[2];
        #pragma unroll
        for (int mi = 0; mi < 2; ++mi) {
            int m = mi * 16 + lc;
            int mPg = 32 * b + m;
            int mc = mPg < nP ? mPg : nP - 1;
            mcl[mi] = mc - 32 * b;
            px[mi] = xall + (size_t)(startP + mc) * 128 + koff;
        }
        const ushort* pb = Bpack + (size_t)bn * 49152 + (size_t)seg * 1024
                                 + (size_t)(wn * 64 + lc) * 8;

        f32x4 acc[2][4];
        #pragma unroll
        for (int mi = 0; mi < 2; ++mi)
            #pragma unroll
            for (int f = 0; f < 4; ++f) acc[mi][f] = (f32x4){0.f, 0.f, 0.f, 0.f};

        #pragma unroll
        for (int kk = 0; kk < 4; ++kk) {
            s8v a0 = *(const s8v*)(px[0] + kk * 32);
            s8v a1 = *(const s8v*)(px[1] + kk * 32);
            #pragma unroll
            for (int f = 0; f < 4; ++f) {
                s8v bb = *(const s8v*)(pb + (size_t)kk * 4096 + f * 128);
                acc[0][f] = __builtin_amdgcn_mfma_f32_16x16x32_bf16(a0, bb, acc[0][f], 0, 0, 0);
                acc[1][f] = __builtin_amdgcn_mfma_f32_16x16x32_bf16(a1, bb, acc[1][f], 0, 0, 0);
            }
        }
        #pragma unroll
        for (int kk = 0; kk < 8; ++kk) {
            const int hi = kk >> 2, off = (kk & 3) * 32;
            s8v a0 = *(const s8v*)(&hC[2 * mcl[0] + hi][off + koff]);
            s8v a1 = *(const s8v*)(&hC[2 * mcl[1] + hi][off + koff]);
            #pragma unroll
            for (int f = 0; f < 4; ++f) {
                s8v bb = *(const s8v*)(pb + (size_t)(kk + 4) * 4096 + f * 128);
                acc[0][f] = __builtin_amdgcn_mfma_f32_16x16x32_bf16(a0, bb, acc[0][f], 0, 0, 0);
                acc[1][f] = __builtin_amdgcn_mfma_f32_16x16x32_bf16(a1, bb, acc[1][f], 0, 0, 0);
            }
        }

        const int j = bn * 32 + wn * 16 + lc;
        const float bi = bsum[j];
        const float bf = bsum[128 + j];
        const float bg = bsum[256 + j];
        const float bo = bsum[384 + j];
        #pragma unroll
        for (int mi = 0; mi < 2; ++mi) {
            #pragma unroll
            for (int r = 0; r < 4; ++r) {
                const int m = mi * 16 + seg * 4 + r;
                const int mPg = 32 * b + m;
                if (mPg < nP) {
                    const float gi = acc[mi][0][r] + bi;
                    const float gf = acc[mi][1][r] + bf;
                    const float gg = acc[mi][2][r] + bg;
                    const float go = acc[mi][3][r] + bo;
                    const float c0 = cC[m][j];
                    const float cn = sigf(gf) * c0 + sigf(gi) * tanh_fast(gg);
                    const float hn = sigf(go) * tanh_fast(cn);
                    h_out[(size_t)mPg * 128 + j] = f2bf(hn);
                    if (!(mPg & 1)) c_out[(size_t)(mPg >> 1) * 128 + j] = cn;
                }
            }
        }
    }
}

// ---------------- root level (1 node, all 512 cols) + head (R6-proven) ----------------
__global__ __launch_bounds__(256) void root_and_head(
    const int* __restrict__ nt, const float* __restrict__ na,
    const float* __restrict__ emb,
    const ushort* __restrict__ Bpack, const float* __restrict__ bsum,
    const ushort* __restrict__ h_in, const float* __restrict__ c_in,
    const float* __restrict__ W1, const float* __restrict__ b1,
    const float* __restrict__ W2, const float* __restrict__ b2,
    const float* __restrict__ vmask, float* __restrict__ out)
{
    __shared__ float hs[128];
    __shared__ float as[128];
    const int tid  = threadIdx.x;
    const int lane = tid & 63;
    const int bn   = tid >> 6;
    const int lc = lane & 15, seg = lane >> 4;
    const int koff = seg * 8;

    const int   ty  = nt[0];
    const float arg = na[0];
    const ushort* ph0 = h_in + koff;
    const ushort* ph1 = h_in + 128 + koff;
    const ushort* pb = Bpack + (size_t)bn * 49152 + (size_t)seg * 1024 + (size_t)lc * 8;

    f32x4 acc[8];
    #pragma unroll
    for (int f = 0; f < 8; ++f) acc[f] = (f32x4){0.f, 0.f, 0.f, 0.f};

    #pragma unroll
    for (int kk = 0; kk < 4; ++kk) {
        const float* src = emb + (size_t)ty * 128 + kk * 32 + koff;
        float4 w0 = *(const float4*)src;
        float4 w1 = *(const float4*)(src + 4);
        ushort o[8] = { f2bf(w0.x), f2bf(w0.y), f2bf(w0.z), f2bf(w0.w),
                        f2bf(w1.x), f2bf(w1.y), f2bf(w1.z), f2bf(w1.w) };
        if (kk == 3 && seg == 3 && (ty == 1 || ty == 2)) o[7] = f2bf(arg);
        s8v a = *(const s8v*)o;
        #pragma unroll
        for (int f = 0; f < 8; ++f) {
            s8v b = *(const s8v*)(pb + (size_t)kk * 4096 + f * 128);
            acc[f] = __builtin_amdgcn_mfma_f32_16x16x32_bf16(a, b, acc[f], 0, 0, 0);
        }
    }
    #pragma unroll
    for (int kk = 0; kk < 8; ++kk) {
        s8v a = *(const s8v*)(((kk >> 2) ? ph1 : ph0) + (kk & 3) * 32);
        #pragma unroll
        for (int f = 0; f < 8; ++f) {
            s8v b = *(const s8v*)(pb + (size_t)(kk + 4) * 4096 + f * 128);
            acc[f] = __builtin_amdgcn_mfma_f32_16x16x32_bf16(a, b, acc[f], 0, 0, 0);
        }
    }

    if (seg == 0) {
        #pragma unroll
        for (int bh = 0; bh < 2; ++bh) {
            const int j = bn * 32 + bh * 16 + lc;
            const float gi = acc[bh * 4 + 0][0] + bsum[j];
            const float gf = acc[bh * 4 + 1][0] + bsum[128 + j];
            const float gg = acc[bh * 4 + 2][0] + bsum[256 + j];
            const float go = acc[bh * 4 + 3][0] + bsum[384 + j];
            const float cn = sigf(gf) * c_in[j] + sigf(gi) * tanh_fast(gg);
            hs[j] = sigf(go) * tanh_fast(cn);
        }
    }
    __syncthreads();
    if (tid < 128) {
        float a1 = b1[tid];
        #pragma unroll 4
        for (int k = 0; k < 128; ++k) a1 = fmaf(hs[k], W1[tid * 128 + k], a1);
        as[tid] = fmaxf(a1, 0.0f);
    }
    __syncthreads();
    if (tid < 32) {
        float l = b2[tid];
        #pragma unroll 4
        for (int k = 0; k < 128; ++k) l = fmaf(as[k], W2[tid * 128 + k], l);
        l = (l + logf(vmask[tid])) * (1.0f / 3.0f);
        float mx = l;
        #pragma unroll
        for (int o = 16; o >= 1; o >>= 1) mx = fmaxf(mx, __shfl_xor(mx, o, 32));
        const float e = __expf(l - mx);
        float s = e;
        #pragma unroll
        for (int o = 16; o >= 1; o >>= 1) s += __shfl_xor(s, o, 32);
        out[tid] = e / s;
    }
}

extern "C" void kernel_launch(void* const* d_in, const int* in_sizes, int n_in,
                              void* d_out, int out_size, void* d_ws, size_t ws_size,
                              hipStream_t stream)
{
    const int*   node_types = (const int*)  d_in[0];
    const float* node_args  = (const float*)d_in[1];
    const float* vmask      = (const float*)d_in[2];
    const float* emb        = (const float*)d_in[3];
    const float* Wih        = (const float*)d_in[4];
    const float* Whh        = (const float*)d_in[5];
    const float* bih        = (const float*)d_in[6];
    const float* bhh        = (const float*)d_in[7];
    const float* W1         = (const float*)d_in[8];
    const float* b1         = (const float*)d_in[9];
    const float* W2         = (const float*)d_in[10];
    const float* b2         = (const float*)d_in[11];

    char* w = (char*)d_ws;
    ushort* xall  = (ushort*)(w);                 // 65536*128*2 = 16,777,216
    ushort* Bpack = (ushort*)(w + 16777216);      // 393,216
    float*  bsum  = (float*) (w + 17170432);      // 2,048
    ushort* hA    = (ushort*)(w + 17172480);      // max 16384*128*2 = 4,194,304
    float*  cA    = (float*) (w + 21366784);      // max 8192*128*4  = 4,194,304
    ushort* hB    = (ushort*)(w + 25561088);      // max 4096*128*2  = 1,048,576
    float*  cB    = (float*) (w + 26609664);      // max 2048*128*4  = 1,048,576

    prepass<<<4096, 256, 0, stream>>>(node_types, node_args, emb,
                                      Wih, Whh, bih, bhh, Bpack, bsum, xall);

    // big pairs: (C,P) = (15,14) leaf -> A; (13,12) A->B; (11,10) B->A; (9,8) A->B
    pair_gemm<<<512, 512, 0, stream>>>(xall, Bpack, bsum, hB, cB, hA, cA, 32767, 16383, 16384, 0);
    pair_gemm<<<128, 512, 0, stream>>>(xall, Bpack, bsum, hA, cA, hB, cB,  8191,  4095,  4096, 1);
    pair_gemm<<< 32, 512, 0, stream>>>(xall, Bpack, bsum, hB, cB, hA, cA,  2047,  1023,  1024, 1);
    pair_gemm<<<  8, 512, 0, stream>>>(xall, Bpack, bsum, hA, cA, hB, cB,   511,   255,   256, 1);

    // small levels 7..1: bn-split singles (4 CUs stream 96KB of B each, in parallel)
    const ushort* hp = hB; const float* cp = cB;
    for (int lvl = 7; lvl >= 1; --lvl) {
        const int n_l = 1 << lvl;
        const bool toA = (lvl & 1);              // 7->A, 6->B, 5->A, ... 1->A
        ushort* ho = toA ? hA : hB;
        float*  co = toA ? cA : cB;
        dim3 grid((n_l + 63) / 64, 4);
        level_gemm<<<grid, 256, 0, stream>>>(xall, Bpack, bsum, hp, cp, ho, co,
                                             n_l - 1, n_l, 1);
        hp = ho; cp = co;
    }

    // root (level 0) + head; level-1 outputs are in hA/cA
    root_and_head<<<1, 256, 0, stream>>>(
        node_types, node_args, emb, Bpack, bsum, hA, cA,
        W1, b1, W2, b2, vmask, (float*)d_out);
}

// Round 15
// 192.846 us; speedup vs baseline: 1.6106x; 1.0600x over previous
//
#include <hip/hip_runtime.h>
#include <hip/hip_bf16.h>

typedef __attribute__((ext_vector_type(8))) short s8v;   // 8 x bf16
typedef __attribute__((ext_vector_type(4))) float f32x4; // MFMA acc

__device__ __forceinline__ float sigf(float x) { return 1.0f / (1.0f + __expf(-x)); }
__device__ __forceinline__ float tanh_fast(float x) { return 1.0f - 2.0f / (1.0f + __expf(2.0f * x)); }
__device__ __forceinline__ ushort f2bf(float f) {
    union { __hip_bfloat16 b; ushort u; } v; v.b = __float2bfloat16(f); return v.u;
}

// ---------------- prepass ----------------
// PX[ty*512 + g*128 + j] = dot(emb[ty], Wih[g*256+j]) + bih+bhh   (fp32, 256KB)
// Wcol[g*128+j] = Wih[g*256+j][127]  (rank-1 node_args correction column)
// Bpack (h-part only): (((bn*8 + kk)*4 + seg)*128 + nl)*8 + t, k = 128 + kk*32 + seg*8
//   col order nl -> g=(nl>>4)&3, j = bn*32 + (nl>>6)*16 + (nl&15)
__global__ __launch_bounds__(256) void prepass(
    const float* __restrict__ emb,
    const float* __restrict__ Wih, const float* __restrict__ Whh,
    const float* __restrict__ bih, const float* __restrict__ bhh,
    ushort* __restrict__ Bpack, float* __restrict__ PX, float* __restrict__ Wcol)
{
    const int gid = blockIdx.x * 256 + threadIdx.x;   // 65536 total
    // PX
    {
        const int ty = gid >> 9;
        const int nl = gid & 511;
        const int g = nl >> 7, j = nl & 127;
        const int row = g * 256 + j;
        const float* e = emb + (size_t)ty * 128;
        const float* wr = Wih + (size_t)row * 128;
        float acc = bih[row] + bhh[row];
        #pragma unroll 8
        for (int k = 0; k < 128; k += 4) {
            float4 ev = *(const float4*)(e + k);
            float4 wv = *(const float4*)(wr + k);
            acc = fmaf(ev.x, wv.x, acc);
            acc = fmaf(ev.y, wv.y, acc);
            acc = fmaf(ev.z, wv.z, acc);
            acc = fmaf(ev.w, wv.w, acc);
        }
        PX[gid] = acc;
    }
    if (gid < 16384) {   // B pack (Whh only, K=256)
        const int nl  = gid & 127;
        const int seg = (gid >> 7) & 3;
        const int rest = gid >> 9;        // 0..31
        const int kk = rest & 7;
        const int bn = rest >> 3;
        const int g  = (nl >> 4) & 3;
        const int j  = bn * 32 + ((nl >> 6) << 4) + (nl & 15);
        const int row = g * 256 + j;
        const int k = kk * 32 + seg * 8;
        const float* src = Whh + (size_t)row * 256 + k;
        float4 w0 = *(const float4*)(src);
        float4 w1 = *(const float4*)(src + 4);
        ushort o[8] = { f2bf(w0.x), f2bf(w0.y), f2bf(w0.z), f2bf(w0.w),
                        f2bf(w1.x), f2bf(w1.y), f2bf(w1.z), f2bf(w1.w) };
        *(s8v*)(Bpack + (size_t)gid * 8) = *(const s8v*)o;
    }
    if (gid < 512) {
        const int row = (gid >> 7) * 256 + (gid & 127);
        Wcol[gid] = Wih[(size_t)row * 128 + 127];
    }
}

// ---------------- stage 2 (shared): parents M=32, N=512, K=256 from LDS children ----------------
template<bool ROOT>
__device__ __forceinline__ void stage2_parents(
    const ushort (*hC)[136], const float (*cC)[132],
    const int* __restrict__ nt, const float* __restrict__ na,
    const ushort* __restrict__ Bpack, const float* __restrict__ PX,
    const float* __restrict__ Wcol, float e1, float e2,
    ushort* __restrict__ h_out, float* __restrict__ c_out, float* hs,
    int startP, int nP, int b)
{
    const int tid  = threadIdx.x;
    const int lane = tid & 63;
    const int wave = tid >> 6;
    const int bn = wave >> 1, wn = wave & 1;
    const int lc = lane & 15, seg = lane >> 4;
    const int koff = seg * 8;

    int mcl[2];
    #pragma unroll
    for (int mi = 0; mi < 2; ++mi) {
        int m = mi * 16 + lc;
        int mPg = 32 * b + m;
        int mc = mPg < nP ? mPg : nP - 1;
        mcl[mi] = mc - 32 * b;
    }
    const ushort* pb = Bpack + (size_t)bn * 32768 + (size_t)seg * 1024
                             + (size_t)(wn * 64 + lc) * 8;

    f32x4 acc[2][4];
    #pragma unroll
    for (int mi = 0; mi < 2; ++mi)
        #pragma unroll
        for (int f = 0; f < 4; ++f) acc[mi][f] = (f32x4){0.f, 0.f, 0.f, 0.f};

    #pragma unroll
    for (int kk = 0; kk < 8; ++kk) {
        const int hi = kk >> 2, off = (kk & 3) * 32;
        s8v a0 = *(const s8v*)(&hC[2 * mcl[0] + hi][off + koff]);
        s8v a1 = *(const s8v*)(&hC[2 * mcl[1] + hi][off + koff]);
        #pragma unroll
        for (int f = 0; f < 4; ++f) {
            s8v bb = *(const s8v*)(pb + (size_t)kk * 4096 + f * 128);
            acc[0][f] = __builtin_amdgcn_mfma_f32_16x16x32_bf16(a0, bb, acc[0][f], 0, 0, 0);
            acc[1][f] = __builtin_amdgcn_mfma_f32_16x16x32_bf16(a1, bb, acc[1][f], 0, 0, 0);
        }
    }

    const int j = bn * 32 + wn * 16 + lc;
    const float wc0 = Wcol[j];
    const float wc1 = Wcol[128 + j];
    const float wc2 = Wcol[256 + j];
    const float wc3 = Wcol[384 + j];
    #pragma unroll
    for (int mi = 0; mi < 2; ++mi) {
        #pragma unroll
        for (int r = 0; r < 4; ++r) {
            const int m = mi * 16 + seg * 4 + r;
            const int mPg = 32 * b + m;
            if (mPg < nP) {
                const int node = startP + mPg;
                const int ty = nt[node];
                const float corr = (ty == 1) ? (na[node] - e1)
                                 : ((ty == 2) ? (na[node] - e2) : 0.0f);
                const float* px = PX + (size_t)ty * 512 + j;
                const float gi = acc[mi][0][r] + px[0]   + corr * wc0;
                const float gf = acc[mi][1][r] + px[128] + corr * wc1;
                const float gg = acc[mi][2][r] + px[256] + corr * wc2;
                const float go = acc[mi][3][r] + px[384] + corr * wc3;
                const float c0 = cC[m][j];
                const float cn = sigf(gf) * c0 + sigf(gi) * tanh_fast(gg);
                const float hn = sigf(go) * tanh_fast(cn);
                if (ROOT) {
                    hs[j] = hn;   // nP==1: only m==0 lanes reach here
                } else {
                    h_out[(size_t)mPg * 128 + j] = f2bf(hn);
                    if (!(mPg & 1)) c_out[(size_t)(mPg >> 1) * 128 + j] = cn;
                }
            }
        }
    }
}

// ---------------- pair (15,14): leaf children via PX gather (no GEMM) + parent GEMM ----------------
__global__ __launch_bounds__(512) void pair_leaf(
    const int* __restrict__ nt, const float* __restrict__ na,
    const float* __restrict__ emb,
    const ushort* __restrict__ Bpack, const float* __restrict__ PX,
    const float* __restrict__ Wcol,
    ushort* __restrict__ h_out, float* __restrict__ c_out)
{
    __shared__ __align__(16) ushort hC[64][136];
    __shared__ float cC[32][132];
    const int tid = threadIdx.x;
    const int b = blockIdx.x;
    const float e1 = emb[255], e2 = emb[383];

    // stage 1: 64 leaf children, pure VALU cell from PX (c0 = 0, gf unused)
    {
        const int jj = tid & 127;
        const int grp = tid >> 7;     // 0..3
        const float wc0 = Wcol[jj];
        const float wc2 = Wcol[256 + jj];
        const float wc3 = Wcol[384 + jj];
        #pragma unroll
        for (int k = 0; k < 16; ++k) {
            const int mloc = grp * 16 + k;
            const int node = 32767 + 64 * b + mloc;
            const int ty = nt[node];
            const float corr = (ty == 1) ? (na[node] - e1)
                             : ((ty == 2) ? (na[node] - e2) : 0.0f);
            const float* px = PX + (size_t)ty * 512 + jj;
            const float gi = px[0]   + corr * wc0;
            const float gg = px[256] + corr * wc2;
            const float go = px[384] + corr * wc3;
            const float cn = sigf(gi) * tanh_fast(gg);
            const float hn = sigf(go) * tanh_fast(cn);
            hC[mloc][jj] = f2bf(hn);
            if (!(mloc & 1)) cC[mloc >> 1][jj] = cn;
        }
    }
    __syncthreads();
    stage2_parents<false>(hC, cC, nt, na, Bpack, PX, Wcol, e1, e2,
                          h_out, c_out, nullptr, 16383, 16384, b);
}

// ---------------- pair (C,P) for internal levels; ROOTHEAD adds level-0 + MLP head ----------------
template<int ROOTHEAD>
__global__ __launch_bounds__(512) void pair_h(
    const int* __restrict__ nt, const float* __restrict__ na,
    const float* __restrict__ emb,
    const ushort* __restrict__ Bpack, const float* __restrict__ PX,
    const float* __restrict__ Wcol,
    const ushort* __restrict__ h_in, const float* __restrict__ c_in,
    ushort* __restrict__ h_out, float* __restrict__ c_out,
    int startC, int startP, int nP,
    const float* __restrict__ W1, const float* __restrict__ b1,
    const float* __restrict__ W2, const float* __restrict__ b2,
    const float* __restrict__ vmask, float* __restrict__ out)
{
    __shared__ __align__(16) ushort hC[64][136];
    __shared__ float cC[32][132];
    __shared__ float hs[128];
    __shared__ float as[128];

    const int tid  = threadIdx.x;
    const int lane = tid & 63;
    const int wave = tid >> 6;
    const int lc = lane & 15, seg = lane >> 4;
    const int koff = seg * 8;
    const int nC = 2 * nP;
    const int b = blockIdx.x;
    const float e1 = emb[255], e2 = emb[383];

    // ===== stage 1: children, M=64, N=512, K=256 (grandchildren h from global) =====
    {
        const int wm2 = wave >> 2;
        const int bn  = wave & 3;
        const ushort* ph[2][2];
        #pragma unroll
        for (int mi = 0; mi < 2; ++mi) {
            int mloc = wm2 * 32 + mi * 16 + lc;
            int cg = 64 * b + mloc;
            int cgc = cg < nC ? cg : nC - 1;
            ph[mi][0] = h_in + (size_t)(2 * cgc) * 128 + koff;
            ph[mi][1] = h_in + (size_t)(2 * cgc + 1) * 128 + koff;
        }
        const ushort* pb = Bpack + (size_t)bn * 32768 + (size_t)seg * 1024
                                 + (size_t)lc * 8;

        f32x4 acc[2][8];
        #pragma unroll
        for (int mi = 0; mi < 2; ++mi)
            #pragma unroll
            for (int f = 0; f < 8; ++f) acc[mi][f] = (f32x4){0.f, 0.f, 0.f, 0.f};

        #pragma unroll
        for (int kk = 0; kk < 8; ++kk) {
            const int hi = kk >> 2, off = (kk & 3) * 32;
            s8v a0 = *(const s8v*)(ph[0][hi] + off);
            s8v a1 = *(const s8v*)(ph[1][hi] + off);
            #pragma unroll
            for (int f = 0; f < 8; ++f) {
                s8v bb = *(const s8v*)(pb + (size_t)kk * 4096 + f * 128);
                acc[0][f] = __builtin_amdgcn_mfma_f32_16x16x32_bf16(a0, bb, acc[0][f], 0, 0, 0);
                acc[1][f] = __builtin_amdgcn_mfma_f32_16x16x32_bf16(a1, bb, acc[1][f], 0, 0, 0);
            }
        }
        #pragma unroll
        for (int bh = 0; bh < 2; ++bh) {
            const int j = bn * 32 + bh * 16 + lc;
            const float wc0 = Wcol[j];
            const float wc1 = Wcol[128 + j];
            const float wc2 = Wcol[256 + j];
            const float wc3 = Wcol[384 + j];
            #pragma unroll
            for (int mi = 0; mi < 2; ++mi) {
                #pragma unroll
                for (int r = 0; r < 4; ++r) {
                    const int mloc = wm2 * 32 + mi * 16 + seg * 4 + r;
                    const int cg = 64 * b + mloc;
                    if (cg < nC) {
                        const int node = startC + cg;
                        const int ty = nt[node];
                        const float corr = (ty == 1) ? (na[node] - e1)
                                         : ((ty == 2) ? (na[node] - e2) : 0.0f);
                        const float* px = PX + (size_t)ty * 512 + j;
                        const float gi = acc[mi][bh * 4 + 0][r] + px[0]   + corr * wc0;
                        const float gf = acc[mi][bh * 4 + 1][r] + px[128] + corr * wc1;
                        const float gg = acc[mi][bh * 4 + 2][r] + px[256] + corr * wc2;
                        const float go = acc[mi][bh * 4 + 3][r] + px[384] + corr * wc3;
                        const float c0 = c_in[(size_t)cg * 128 + j];
                        const float cn = sigf(gf) * c0 + sigf(gi) * tanh_fast(gg);
                        const float hn = sigf(go) * tanh_fast(cn);
                        hC[mloc][j] = f2bf(hn);
                        if (!(mloc & 1)) cC[mloc >> 1][j] = cn;
                    }
                }
            }
        }
    }
    __syncthreads();

    // ===== stage 2: parents =====
    if (ROOTHEAD) {
        stage2_parents<true>(hC, cC, nt, na, Bpack, PX, Wcol, e1, e2,
                             nullptr, nullptr, hs, startP, nP, b);
        __syncthreads();
        if (tid < 128) {
            float a1h = b1[tid];
            #pragma unroll 4
            for (int k = 0; k < 128; ++k) a1h = fmaf(hs[k], W1[tid * 128 + k], a1h);
            as[tid] = fmaxf(a1h, 0.0f);
        }
        __syncthreads();
        if (tid < 32) {
            float l = b2[tid];
            #pragma unroll 4
            for (int k = 0; k < 128; ++k) l = fmaf(as[k], W2[tid * 128 + k], l);
            l = (l + logf(vmask[tid])) * (1.0f / 3.0f);
            float mx = l;
            #pragma unroll
            for (int o = 16; o >= 1; o >>= 1) mx = fmaxf(mx, __shfl_xor(mx, o, 32));
            const float e = __expf(l - mx);
            float s = e;
            #pragma unroll
            for (int o = 16; o >= 1; o >>= 1) s += __shfl_xor(s, o, 32);
            out[tid] = e / s;
        }
    } else {
        stage2_parents<false>(hC, cC, nt, na, Bpack, PX, Wcol, e1, e2,
                              h_out, c_out, nullptr, startP, nP, b);
    }
}

extern "C" void kernel_launch(void* const* d_in, const int* in_sizes, int n_in,
                              void* d_out, int out_size, void* d_ws, size_t ws_size,
                              hipStream_t stream)
{
    const int*   node_types = (const int*)  d_in[0];
    const float* node_args  = (const float*)d_in[1];
    const float* vmask      = (const float*)d_in[2];
    const float* emb        = (const float*)d_in[3];
    const float* Wih        = (const float*)d_in[4];
    const float* Whh        = (const float*)d_in[5];
    const float* bih        = (const float*)d_in[6];
    const float* bhh        = (const float*)d_in[7];
    const float* W1         = (const float*)d_in[8];
    const float* b1         = (const float*)d_in[9];
    const float* W2         = (const float*)d_in[10];
    const float* b2         = (const float*)d_in[11];

    char* w = (char*)d_ws;
    ushort* Bpack = (ushort*)(w);                 // 16384*8*2   =   262,144
    float*  PX    = (float*) (w + 262144);        // 65536*4     =   262,144
    float*  Wcol  = (float*) (w + 524288);        // 512*4       =     2,048
    ushort* hA    = (ushort*)(w + 526336);        // 16384*128*2 = 4,194,304
    float*  cA    = (float*) (w + 4720640);       // 8192*128*4  = 4,194,304
    ushort* hB    = (ushort*)(w + 8914944);       // 4096*128*2  = 1,048,576
    float*  cB    = (float*) (w + 9963520);       // 2048*128*4  = 1,048,576

    float* out = (float*)d_out;

    prepass<<<256, 256, 0, stream>>>(emb, Wih, Whh, bih, bhh, Bpack, PX, Wcol);

    // (15,14) leaf -> A
    pair_leaf<<<512, 512, 0, stream>>>(node_types, node_args, emb,
                                       Bpack, PX, Wcol, hA, cA);
    // internal pairs
    pair_h<0><<<128, 512, 0, stream>>>(node_types, node_args, emb, Bpack, PX, Wcol,
        hA, cA, hB, cB, 8191, 4095, 4096, nullptr, nullptr, nullptr, nullptr, nullptr, nullptr);
    pair_h<0><<< 32, 512, 0, stream>>>(node_types, node_args, emb, Bpack, PX, Wcol,
        hB, cB, hA, cA, 2047, 1023, 1024, nullptr, nullptr, nullptr, nullptr, nullptr, nullptr);
    pair_h<0><<<  8, 512, 0, stream>>>(node_types, node_args, emb, Bpack, PX, Wcol,
        hA, cA, hB, cB,  511,  255,  256, nullptr, nullptr, nullptr, nullptr, nullptr, nullptr);
    pair_h<0><<<  2, 512, 0, stream>>>(node_types, node_args, emb, Bpack, PX, Wcol,
        hB, cB, hA, cA,  127,   63,   64, nullptr, nullptr, nullptr, nullptr, nullptr, nullptr);
    pair_h<0><<<  1, 512, 0, stream>>>(node_types, node_args, emb, Bpack, PX, Wcol,
        hA, cA, hB, cB,   31,   15,   16, nullptr, nullptr, nullptr, nullptr, nullptr, nullptr);
    pair_h<0><<<  1, 512, 0, stream>>>(node_types, node_args, emb, Bpack, PX, Wcol,
        hB, cB, hA, cA,    7,    3,    4, nullptr, nullptr, nullptr, nullptr, nullptr, nullptr);
    // (1,0) + head: children level 1 (reads level-2 h/c from A), root + MLP + softmax
    pair_h<1><<<  1, 512, 0, stream>>>(node_types, node_args, emb, Bpack, PX, Wcol,
        hA, cA, hB, cB,    1,    0,    1, W1, b1, W2, b2, vmask, out);
}